// Round 9
// baseline (370.550 us; speedup 1.0000x reference)
//
#include <hip/hip_runtime.h>
#include <hip/hip_bf16.h>
#include <cstdint>

typedef unsigned short u16;
typedef short v8s __attribute__((ext_vector_type(8)));   // 8 bf16 (4 VGPRs) MFMA A/B frag
typedef float v4f __attribute__((ext_vector_type(4)));   // MFMA C/D frag
typedef u16 u16x8 __attribute__((ext_vector_type(8)));
typedef u16 u16x4 __attribute__((ext_vector_type(4)));

static constexpr int Bb = 8, Cc = 512, Ll = 2048, Hh = 8, Dh = 64;

__device__ __forceinline__ float bf2f(u16 u){
  unsigned x = ((unsigned)u) << 16; float f; __builtin_memcpy(&f, &x, 4); return f;
}
__device__ __forceinline__ u16 f2bf(float f){
  unsigned x; __builtin_memcpy(&x, &f, 4);
  x = (x + 0x7fffu + ((x >> 16) & 1u)) >> 16; return (u16)x;  // RNE
}

__device__ __forceinline__ void async_cp16(const u16* g, u16* l){
  __builtin_amdgcn_global_load_lds(
      (const __attribute__((address_space(1))) unsigned int*)g,
      (__attribute__((address_space(3))) unsigned int*)l, 16, 0, 0);
}

#if __has_builtin(__builtin_amdgcn_exp2f)
#define EXP2F(x) __builtin_amdgcn_exp2f(x)
#else
#define EXP2F(x) exp2f(x)
#endif

// ---------------- dtype detector (flag: 1 = fp32 inputs)
__global__ __launch_bounds__(256) void detect_dtype(const u16* __restrict__ x, unsigned* __restrict__ flag){
  __shared__ int cnt;
  if (threadIdx.x == 0) cnt = 0;
  __syncthreads();
  int sane = 0;
  for (int i = threadIdx.x; i < 4096; i += 256){
    unsigned e = (x[2 * i] >> 7) & 0xFFu;
    sane += (e >= 90u && e <= 160u) ? 1 : 0;
  }
  atomicAdd(&cnt, sane);
  __syncthreads();
  if (threadIdx.x == 0) *flag = (cnt < 2458) ? 1u : 0u;
}

// ---------------- transpose + pad (zeroes boundary rows itself; no memset needed)
__global__ __launch_bounds__(256) void transpose_pad(const void* __restrict__ xv, const unsigned* __restrict__ flagp,
                                                     u16* __restrict__ xT){
  int b = blockIdx.z, ci0 = blockIdx.y * 64, l0 = blockIdx.x * 64;
  __shared__ u16 tb[64 * 72];             // [l][ci], stride 72 pad
  const unsigned isf32 = *flagp;
  int t = threadIdx.x;
  int row = t >> 3, seg = t & 7;
  if (isf32){
    const float* xf = (const float*)xv;
    #pragma unroll
    for (int rnd = 0; rnd < 2; rnd++){
      int ci = row + rnd * 32;
      size_t off = ((size_t)(b * Cc + ci0 + ci)) * Ll + l0 + seg * 8;
      v4f a = *(const v4f*)(xf + off);
      v4f c4 = *(const v4f*)(xf + off + 4);
      #pragma unroll
      for (int j = 0; j < 4; j++) tb[(seg * 8 + j) * 72 + ci] = f2bf(a[j]);
      #pragma unroll
      for (int j = 0; j < 4; j++) tb[(seg * 8 + 4 + j) * 72 + ci] = f2bf(c4[j]);
    }
  } else {
    const u16* x = (const u16*)xv;
    #pragma unroll
    for (int rnd = 0; rnd < 2; rnd++){
      int ci = row + rnd * 32;
      u16x8 v = *(const u16x8*)(x + ((size_t)(b * Cc + ci0 + ci)) * Ll + l0 + seg * 8);
      #pragma unroll
      for (int j = 0; j < 8; j++) tb[(seg * 8 + j) * 72 + ci] = v[j];
    }
  }
  __syncthreads();
  #pragma unroll
  for (int rnd = 0; rnd < 2; rnd++){
    int l = row + rnd * 32;
    u16x8 v = *(const u16x8*)&tb[l * 72 + seg * 8];
    *(u16x8*)(xT + ((size_t)b * 2050 + 1 + l0 + l) * Cc + ci0 + seg * 8) = v;
  }
  // zero pad rows 0 / 2049
  if (blockIdx.x == 0 && t < 8){
    u16x8 z = {};
    *(u16x8*)(xT + ((size_t)b * 2050 + 0) * Cc + ci0 + t * 8) = z;
  }
  if (blockIdx.x == 31 && t < 8){
    u16x8 z = {};
    *(u16x8*)(xT + ((size_t)b * 2050 + 2049) * Cc + ci0 + t * 8) = z;
  }
}

// ---------------- weight + bias repack: wp[((conv*3+k)*512+co)*512+ci] = w_conv[co][ci][k]; bb appended
__global__ __launch_bounds__(256) void pack_wb(const void* __restrict__ w0, const void* __restrict__ w1,
                                               const void* __restrict__ w2, const void* __restrict__ b0,
                                               const void* __restrict__ b1, const void* __restrict__ b2,
                                               const unsigned* __restrict__ flagp,
                                               u16* __restrict__ wp, u16* __restrict__ bb){
  int g = blockIdx.x * 256 + threadIdx.x;
  const unsigned isf32 = *flagp;
  if (g < 9 * 512 * 512){
    int ci = g & 511, co = (g >> 9) & 511, kc = g >> 18;   // kc = conv*3+k
    int conv = kc / 3, k = kc - conv * 3;
    const void* w = (conv == 0) ? w0 : ((conv == 1) ? w1 : w2);
    size_t idx = (size_t)co * 1536 + ci * 3 + k;
    wp[g] = isf32 ? f2bf(((const float*)w)[idx]) : ((const u16*)w)[idx];
  } else {
    int g2 = g - 9 * 512 * 512;
    if (g2 < 1536){
      int conv = g2 >> 9, c = g2 & 511;
      const void* bsrc = (conv == 0) ? b0 : ((conv == 1) ? b1 : b2);
      bb[g2] = isf32 ? f2bf(((const float*)bsrc)[c]) : ((const u16*)bsrc)[c];
    }
  }
}

// ---------------- fused conv GEMM: A global->REGISTER (skip LDS), B LDS triple-buffer.
// R8 diagnosis: LDS-read pipe (128 b128/kt = 1536 cyc) > MFMA pipe (1242 cyc) -> LDS-BW
// bound. Fix: A fragments are contiguous 16B chunks in wp -> load direct to VGPR from L2
// (double-buffered afP/afQ one kt ahead, statically indexed via explicit 2-unroll).
// LDS now carries only B: 64 b128 reads + 32 KiB DMA writes = ~1024 cyc < MFMA 1242.
// 128M x 256N tile, BK=64, 768 blocks = 3 full rounds. Issue order pinned per kt:
// [8 A-loads][4 B-stages(kt+2)] -> end-of-kt vmcnt(4) leaves only B(kt+2) in flight,
// certifies A(kt+1)+B(kt+1). Never drain to 0 until kt=22. B XOR-swizzle (0 conflicts).
__global__ __launch_bounds__(512, 2) void conv_gemm_fused(const u16* __restrict__ wp, const u16* __restrict__ xT,
                                                          const u16* __restrict__ bb, u16* __restrict__ qT,
                                                          u16* __restrict__ kT, u16* __restrict__ vN){
  __shared__ u16 smem[49152];   // 96 KiB: 3 B-bufs x 16384 elems (256 rows x 64)
  int bx = blockIdx.x;
  int b = bx & 7, inner = bx >> 3;            // b -> XCD (one batch per XCD L2)
  int mt = inner >> 3, nt = inner & 7;        // mt 0..11, nt 0..7
  int m0 = mt << 7, n0 = nt << 8;
  int conv = m0 >> 9, co0 = m0 & 511;

  int t = threadIdx.x, wave = t >> 6, lane = t & 63, quad = lane >> 4, lid = lane & 15;
  int wm_i = wave >> 2, wn_i = wave & 3;      // 2M x 4N

  // B read-side swizzle: byte-col ^= (row&7)<<4; all frag rows have row%8 == lid%8
  int sx = (lid & 7) << 4;                               // byte XOR
  int cb0 = ((quad * 16) ^ sx) >> 1;                     // elem col, kh=0
  int cb1 = ((64 + quad * 16) ^ sx) >> 1;                // elem col, kh=1
  int bbase0 = (wn_i * 64 + lid) * 64;                   // elem, B region (256 rows)

  // B staging map: LDS linear byte p (row=p>>7, cb=p&127) <- global col cb ^ ((row&7)<<4)
  int srcB[4];
  #pragma unroll
  for (int r = 0; r < 4; r++){
    int p = t * 16 + r * 8192;                 // byte into 32 KiB B region
    int row = p >> 7, c = (p & 127) ^ ((row & 7) << 4);
    srcB[r] = row * 512 + (c >> 1);
  }

  const u16* aGbase = wp + (size_t)(conv * 1536 + co0) * 512;
  const u16* bGbase = xT + (size_t)b * (2050 * 512) + (size_t)n0 * 512;
  const int arow = (wm_i * 64 + lid) * 512 + quad * 8;   // per-thread A offset within panel

#define LOAD_AG(dst, k1) do{ \
    int ks1_ = (k1) >> 3, ci1_ = ((k1) & 7) << 6; \
    const u16* aG_ = aGbase + (size_t)ks1_ * 262144 + ci1_ + arow; \
    _Pragma("unroll") for (int m = 0; m < 4; ++m){ \
      dst[m][0] = *(const v8s*)(aG_ + m * 8192); \
      dst[m][1] = *(const v8s*)(aG_ + m * 8192 + 32); } }while(0)

#define STAGE_B(k2) do{ \
    int ks2_ = (k2) >> 3, ci2_ = ((k2) & 7) << 6; \
    const u16* bG_ = bGbase + (size_t)ks2_ * 512 + ci2_; \
    u16* stg_ = smem + ((k2) % 3) * 16384; \
    _Pragma("unroll") for (int r = 0; r < 4; ++r) \
      async_cp16(bG_ + srcB[r], stg_ + t * 8 + r * 4096); }while(0)

#define LOAD_Bn(n) do{ \
    bfc[0] = *(const v8s*)(lds + bbase0 + (n) * 1024 + cb0); \
    bfc[1] = *(const v8s*)(lds + bbase0 + (n) * 1024 + cb1); }while(0)

#define MFMA_COL(AC, n) do{ \
    __builtin_amdgcn_s_setprio(1); \
    _Pragma("unroll") for (int m = 0; m < 4; ++m) \
    _Pragma("unroll") for (int kh = 0; kh < 2; ++kh) \
      acc[m][n] = __builtin_amdgcn_mfma_f32_16x16x32_bf16(AC[m][kh], bfc[kh], acc[m][n], 0, 0, 0); \
    __builtin_amdgcn_s_setprio(0); }while(0)

#define KT_BODY(AC, AN, kt) do{ \
    u16* lds = smem + ((kt) % 3) * 16384; \
    if ((kt) < 23) LOAD_AG(AN, (kt) + 1); \
    __builtin_amdgcn_sched_barrier(0); \
    if ((kt) < 22) STAGE_B((kt) + 2); \
    __builtin_amdgcn_sched_barrier(0); \
    v8s bfc[2]; \
    LOAD_Bn(0); MFMA_COL(AC, 0); \
    LOAD_Bn(1); MFMA_COL(AC, 1); \
    LOAD_Bn(2); MFMA_COL(AC, 2); \
    LOAD_Bn(3); MFMA_COL(AC, 3); \
    if ((kt) < 22){ \
      asm volatile("s_waitcnt vmcnt(4)" ::: "memory"); \
      __builtin_amdgcn_sched_barrier(0); \
      __builtin_amdgcn_s_barrier(); \
    } else if ((kt) == 22){ \
      asm volatile("s_waitcnt vmcnt(0)" ::: "memory"); \
      __builtin_amdgcn_sched_barrier(0); \
      __builtin_amdgcn_s_barrier(); \
    } }while(0)

  v4f acc[4][4] = {};   // [m][n]
  v8s afP[4][2], afQ[4][2];

  // ---- prologue: A(0) -> afP; stage B(0),B(1); vmcnt(4) leaves B(1), certifies A(0)+B(0)
  LOAD_AG(afP, 0);
  __builtin_amdgcn_sched_barrier(0);
  STAGE_B(0);
  STAGE_B(1);
  asm volatile("s_waitcnt vmcnt(4)" ::: "memory");
  __builtin_amdgcn_sched_barrier(0);
  __builtin_amdgcn_s_barrier();

  // ---- main loop: 24 K-tiles (3 taps x 8 ci-steps), explicit 2-unroll for reg ping-pong
  for (int kt2 = 0; kt2 < 24; kt2 += 2){
    KT_BODY(afP, afQ, kt2);
    KT_BODY(afQ, afP, kt2 + 1);
  }

#undef LOAD_AG
#undef STAGE_B
#undef LOAD_Bn
#undef MFMA_COL
#undef KT_BODY

  // ---- epilogue
  const float qsc = (float)(1.4426950408889634 / 22.627416997969522);
  if (conv < 2){
    u16* dst = (conv == 0) ? qT : kT;
    #pragma unroll
    for (int m = 0; m < 4; ++m){
      int cog = m0 + wm_i * 64 + m * 16 + quad * 4;
      float bv[4];
      #pragma unroll
      for (int r = 0; r < 4; r++) bv[r] = bf2f(bb[cog + r]);
      int coc = cog & 511;
      #pragma unroll
      for (int n = 0; n < 4; ++n){
        int l = n0 + wn_i * 64 + n * 16 + lid;
        u16x4 pk;
        #pragma unroll
        for (int r = 0; r < 4; r++){
          float v = acc[m][n][r] + bv[r];
          if (conv == 0) v *= qsc;
          pk[r] = f2bf(v);
        }
        *(u16x4*)(dst + ((((size_t)b * Hh + (coc >> 6)) * Ll + l) << 6) + (coc & 63)) = pk;
      }
    }
  } else {
    // v: LDS-bounce transpose -> vectorized [b][co][l] stores. scr = [128 co][264]
    u16* scr = smem;
    __syncthreads();
    #pragma unroll
    for (int m = 0; m < 4; ++m){
      int rloc = wm_i * 64 + m * 16 + quad * 4;
      int cog = m0 + rloc;
      float bv[4];
      #pragma unroll
      for (int r = 0; r < 4; r++) bv[r] = bf2f(bb[cog + r]);
      #pragma unroll
      for (int n = 0; n < 4; ++n){
        int lcl = wn_i * 64 + n * 16 + lid;
        #pragma unroll
        for (int r = 0; r < 4; r++)
          scr[(rloc + r) * 264 + lcl] = f2bf(acc[m][n][r] + bv[r]);
      }
    }
    __syncthreads();
    int seg = t & 31, rw = t >> 5;        // seg 0..31 (8-elem cols), rw 0..15
    #pragma unroll
    for (int ps = 0; ps < 8; ++ps){
      int row = rw + ps * 16;
      u16x8 vv = *(const u16x8*)&scr[row * 264 + seg * 8];
      *(u16x8*)(vN + (((size_t)b * Cc + co0 + row) << 11) + n0 + seg * 8) = vv;
    }
  }
}

// ---------------- flash attention: 8-wave (512-thread) blocks for TLP — 512 blocks,
// 2 blocks/CU resident (LDS-limited: 64 KiB/block), 16 waves/CU (50% occupancy).
// NO launch-bounds wave minimum: LDS already pins occupancy; a register cap here caused
// a catastrophic spill (R7: VGPR 64, 715 MB scratch writes, 3.3x slowdown).
// Each wave owns 32 Q-rows; K/V double-buffered, counted vmcnt (4 DMAs/thread: K2+V2;
// waits 2/4/2, never 0 in loop). V LDS split into two [64][64] half-tiles (128B rows,
// conv-proven 0-conflict XOR). Fixed-max softmax, lsum via ones-MFMA, setprio.
__global__ __launch_bounds__(512) void attn_kernel(const u16* __restrict__ qT, const u16* __restrict__ kT,
                                                   const u16* __restrict__ vN, const unsigned* __restrict__ flagp,
                                                   void* __restrict__ outv){
  int bhx = blockIdx.x;                 // 0..63
  int b = bhx >> 3, h = bhx & 7, l0 = blockIdx.y * 256;
  int t = threadIdx.x, w = t >> 6, lane = t & 63, quad = lane >> 4, lid = lane & 15;
  __shared__ u16 kls[2][8192];          // K tile [slot 128][d 64], XOR-swizzled
  __shared__ u16 vls[2][8192];          // V tile [half 2][d 64][m 64], XOR-swizzled
  const unsigned isf32 = *flagp;
  const size_t bh = (size_t)b * Hh + h;
  const int xk = (lid & 7) << 3;        // read-side elem XOR (8-elem granule)

  // staging maps (loop-invariant): dest linear e=(r*512+t)*8; source pre-swizzled.
  // K: slot=e>>6 col=e&63; global row = perm(slot); col ^= (slot&7)<<3.
  // V: half=e>>12 d=(e>>6)&63 col=e&63; global elem = d*2048 + half*64 + (col^((d&7)<<3)).
  int kadd[2], vadd[2];
  #pragma unroll
  for (int r = 0; r < 2; r++){
    int e = (r * 512 + t) * 8;
    int slot = e >> 6, col = e & 63;
    int s5 = slot & 31;
    int m = (slot & ~31) | (((s5 >> 2) & 1) << 3) | (((s5 >> 3) & 1) << 4) | (((s5 >> 4) & 1) << 2) | (s5 & 3);
    kadd[r] = m * 64 + (col ^ ((slot & 7) << 3));
    int half = e >> 12, d = (e >> 6) & 63;
    vadd[r] = d * Ll + half * 64 + (col ^ ((d & 7) << 3));
  }
  const u16* kTb = kT + bh * Ll * 64;
  const u16* vNb = vN + ((size_t)(b * Cc + h * Dh)) * Ll;

#define STAGE_KV(mt1) do{ \
    const u16* kp = kTb + (size_t)(mt1) * 8192; \
    const u16* vp = vNb + (mt1) * 128; \
    u16* kd = &kls[(mt1) & 1][0]; \
    u16* vd = &vls[(mt1) & 1][0]; \
    async_cp16(kp + kadd[0], kd + t * 8); \
    async_cp16(kp + kadd[1], kd + 4096 + t * 8); \
    async_cp16(vp + vadd[0], vd + t * 8); \
    async_cp16(vp + vadd[1], vd + 4096 + t * 8); }while(0)

  // Q fragments in registers (B-operand of S^T GEMM) — issued BEFORE staging so the
  // prologue vmcnt(2) also certifies them (V(0)'s 2 DMAs are the only ones left in flight)
  v8s qF[2][2];
  #pragma unroll
  for (int ci = 0; ci < 2; ci++)
    #pragma unroll
    for (int ks = 0; ks < 2; ks++)
      qF[ci][ks] = *(const v8s*)(qT + ((bh * Ll) + l0 + w * 32 + ci * 16 + lid) * 64 + ks * 32 + quad * 8);
  __builtin_amdgcn_sched_barrier(0);

  const v8s onesF = {0x3F80, 0x3F80, 0x3F80, 0x3F80, 0x3F80, 0x3F80, 0x3F80, 0x3F80};
  v4f o[2][4] = {};                // [ci][df]
  v4f o1[2] = {};                  // lsum accumulators (all cols equal)

  // prologue: stage mt=0; certify Q + K(0) (leave V(0)'s 2 DMAs in flight)
  STAGE_KV(0);
  asm volatile("s_waitcnt vmcnt(2)" ::: "memory");
  __builtin_amdgcn_sched_barrier(0);
  __builtin_amdgcn_s_barrier();

  for (int mt = 0; mt < 16; mt++){
    if (mt < 15) STAGE_KV(mt + 1);              // 4 DMAs; V(mt)'s 2 still in flight
    const u16* kcur = &kls[mt & 1][0];
    const u16* vcur = &vls[mt & 1][0];

    // S^T: s[c][tt][ci] reg r = S^T[m0 + c*32 + quad*8 + tt*4 + r][w*32+ci*16+lid]
    v4f s[4][2][2] = {};
    #pragma unroll
    for (int ks = 0; ks < 2; ks++){
      v8s aF[4][2];
      #pragma unroll
      for (int c = 0; c < 4; c++)
        #pragma unroll
        for (int tt = 0; tt < 2; tt++)
          aF[c][tt] = *(const v8s*)&kcur[(c * 32 + tt * 16 + lid) * 64 + ((ks * 32 + quad * 8) ^ xk)];
      __builtin_amdgcn_s_setprio(1);
      #pragma unroll
      for (int c = 0; c < 4; c++)
        #pragma unroll
        for (int tt = 0; tt < 2; tt++){
          s[c][tt][0] = __builtin_amdgcn_mfma_f32_16x16x32_bf16(aF[c][tt], qF[0][ks], s[c][tt][0], 0, 0, 0);
          s[c][tt][1] = __builtin_amdgcn_mfma_f32_16x16x32_bf16(aF[c][tt], qF[1][ks], s[c][tt][1], 0, 0, 0);
        }
      __builtin_amdgcn_s_setprio(0);
    }

    // V(mt) certified for all waves: own-wave counted wait + barrier
    if (mt < 15){
      asm volatile("s_waitcnt vmcnt(4)" ::: "memory");   // V(mt) landed; K/V(mt+1) in flight
    } else {
      asm volatile("s_waitcnt vmcnt(0)" ::: "memory");
    }
    __builtin_amdgcn_sched_barrier(0);
    __builtin_amdgcn_s_barrier();

    // fixed-max softmax: p = exp2(s) packed straight into PV A-frags; lsum via ones-MFMA
    #pragma unroll
    for (int c = 0; c < 4; c++){
      v8s aP[2];
      #pragma unroll
      for (int ci = 0; ci < 2; ci++){
        float p[8];
        #pragma unroll
        for (int tt = 0; tt < 2; tt++)
          #pragma unroll
          for (int r = 0; r < 4; r++)
            p[tt * 4 + r] = EXP2F(s[c][tt][ci][r]);
        unsigned u[4];
        #pragma unroll
        for (int k2 = 0; k2 < 4; k2++){
          __hip_bfloat162 hb = __float22bfloat162_rn(make_float2(p[2 * k2], p[2 * k2 + 1]));
          __builtin_memcpy(&u[k2], &hb, 4);
        }
        __builtin_memcpy(&aP[ci], u, 16);
      }
      // V reads: half-tile layout, 128B rows, conv-proven XOR pattern
      v8s bV[4];
      #pragma unroll
      for (int df = 0; df < 4; df++)
        bV[df] = *(const v8s*)&vcur[(c >> 1) * 4096 + (df * 16 + lid) * 64 + ((((c & 1) * 32) + quad * 8) ^ xk)];
      __builtin_amdgcn_s_setprio(1);
      #pragma unroll
      for (int ci = 0; ci < 2; ci++){
        #pragma unroll
        for (int df = 0; df < 4; df++)
          o[ci][df] = __builtin_amdgcn_mfma_f32_16x16x32_bf16(aP[ci], bV[df], o[ci][df], 0, 0, 0);
        o1[ci] = __builtin_amdgcn_mfma_f32_16x16x32_bf16(aP[ci], onesF, o1[ci], 0, 0, 0);
      }
      __builtin_amdgcn_s_setprio(0);
    }

    // end of phase: certify K(mt+1) (own-wave) before barrier; V(mt+1) stays in flight
    if (mt < 15){
      asm volatile("s_waitcnt vmcnt(2)" ::: "memory");
      __builtin_amdgcn_sched_barrier(0);
      __builtin_amdgcn_s_barrier();
    }
  }
#undef STAGE_KV

  #pragma unroll
  for (int lf = 0; lf < 2; lf++){
    v4f nv;
    #pragma unroll
    for (int r = 0; r < 4; r++) nv[r] = 1.f / o1[lf][r];
    #pragma unroll
    for (int df = 0; df < 4; df++){
      int d = df * 16 + lid;
      int l = l0 + w * 32 + lf * 16 + quad * 4;
      size_t ofs = (((bh << 6) + d) << 11) + l;
      if (isf32){
        v4f st;
        #pragma unroll
        for (int r = 0; r < 4; r++) st[r] = o[lf][df][r] * nv[r];
        *(v4f*)((float*)outv + ofs) = st;
      } else {
        u16x4 pk;
        #pragma unroll
        for (int r = 0; r < 4; r++) pk[r] = f2bf(o[lf][df][r] * nv[r]);
        *(u16x4*)((u16*)outv + ofs) = pk;
      }
    }
  }
}

extern "C" void kernel_launch(void* const* d_in, const int* in_sizes, int n_in,
                              void* d_out, int out_size, void* d_ws, size_t ws_size,
                              hipStream_t stream){
  const void* x  = d_in[0];
  const void* w0 = d_in[1];
  const void* b0 = d_in[2];
  const void* w1 = d_in[3];
  const void* b1 = d_in[4];
  const void* w2 = d_in[5];
  const void* b2 = d_in[6];
  u16* ws = (u16*)d_ws;
  unsigned* flag = (unsigned*)ws;                // 1 u32 at base (64 u16 slot, aligned)
  u16* xT = ws + 64;                             // [8][2050][512]
  u16* wp = xT + (size_t)8 * 2050 * 512;         // [9][512][512]
  u16* bb = wp + (size_t)9 * 512 * 512;          // [3][512]
  u16* qT = bb + 1536;                           // [8][8][2048][64]
  u16* kT = qT + (size_t)8 * 8 * 2048 * 64;
  u16* vN = kT + (size_t)8 * 8 * 2048 * 64;      // [8][512][2048]

  detect_dtype<<<1, 256, 0, stream>>>((const u16*)x, flag);
  transpose_pad<<<dim3(32, 8, 8), 256, 0, stream>>>(x, flag, xT);
  pack_wb<<<dim3(9 * 512 * 512 / 256 + 6), 256, 0, stream>>>(w0, w1, w2, b0, b1, b2, flag, wp, bb);
  conv_gemm_fused<<<dim3(768), 512, 0, stream>>>(wp, xT, bb, qT, kT, vN);
  attn_kernel<<<dim3(64, 8), 512, 0, stream>>>(qT, kT, vN, flag, d_out);
}

// Round 11
// 269.881 us; speedup vs baseline: 1.3730x; 1.3730x over previous
//
#include <hip/hip_runtime.h>
#include <hip/hip_bf16.h>
#include <cstdint>

typedef unsigned short u16;
typedef short v8s __attribute__((ext_vector_type(8)));   // 8 bf16 (4 VGPRs) MFMA A/B frag
typedef float v4f __attribute__((ext_vector_type(4)));   // MFMA C/D frag
typedef u16 u16x8 __attribute__((ext_vector_type(8)));
typedef u16 u16x4 __attribute__((ext_vector_type(4)));

static constexpr int Bb = 8, Cc = 512, Ll = 2048, Hh = 8, Dh = 64;

__device__ __forceinline__ float bf2f(u16 u){
  unsigned x = ((unsigned)u) << 16; float f; __builtin_memcpy(&f, &x, 4); return f;
}
__device__ __forceinline__ u16 f2bf(float f){
  unsigned x; __builtin_memcpy(&x, &f, 4);
  x = (x + 0x7fffu + ((x >> 16) & 1u)) >> 16; return (u16)x;  // RNE
}

__device__ __forceinline__ void async_cp16(const u16* g, u16* l){
  __builtin_amdgcn_global_load_lds(
      (const __attribute__((address_space(1))) unsigned int*)g,
      (__attribute__((address_space(3))) unsigned int*)l, 16, 0, 0);
}

#if __has_builtin(__builtin_amdgcn_exp2f)
#define EXP2F(x) __builtin_amdgcn_exp2f(x)
#else
#define EXP2F(x) exp2f(x)
#endif

// ---------------- dtype detector (flag: 1 = fp32 inputs)
__global__ __launch_bounds__(256) void detect_dtype(const u16* __restrict__ x, unsigned* __restrict__ flag){
  __shared__ int cnt;
  if (threadIdx.x == 0) cnt = 0;
  __syncthreads();
  int sane = 0;
  for (int i = threadIdx.x; i < 4096; i += 256){
    unsigned e = (x[2 * i] >> 7) & 0xFFu;
    sane += (e >= 90u && e <= 160u) ? 1 : 0;
  }
  atomicAdd(&cnt, sane);
  __syncthreads();
  if (threadIdx.x == 0) *flag = (cnt < 2458) ? 1u : 0u;
}

// ---------------- transpose + pad (zeroes boundary rows itself; no memset needed)
__global__ __launch_bounds__(256) void transpose_pad(const void* __restrict__ xv, const unsigned* __restrict__ flagp,
                                                     u16* __restrict__ xT){
  int b = blockIdx.z, ci0 = blockIdx.y * 64, l0 = blockIdx.x * 64;
  __shared__ u16 tb[64 * 72];             // [l][ci], stride 72 pad
  const unsigned isf32 = *flagp;
  int t = threadIdx.x;
  int row = t >> 3, seg = t & 7;
  if (isf32){
    const float* xf = (const float*)xv;
    #pragma unroll
    for (int rnd = 0; rnd < 2; rnd++){
      int ci = row + rnd * 32;
      size_t off = ((size_t)(b * Cc + ci0 + ci)) * Ll + l0 + seg * 8;
      v4f a = *(const v4f*)(xf + off);
      v4f c4 = *(const v4f*)(xf + off + 4);
      #pragma unroll
      for (int j = 0; j < 4; j++) tb[(seg * 8 + j) * 72 + ci] = f2bf(a[j]);
      #pragma unroll
      for (int j = 0; j < 4; j++) tb[(seg * 8 + 4 + j) * 72 + ci] = f2bf(c4[j]);
    }
  } else {
    const u16* x = (const u16*)xv;
    #pragma unroll
    for (int rnd = 0; rnd < 2; rnd++){
      int ci = row + rnd * 32;
      u16x8 v = *(const u16x8*)(x + ((size_t)(b * Cc + ci0 + ci)) * Ll + l0 + seg * 8);
      #pragma unroll
      for (int j = 0; j < 8; j++) tb[(seg * 8 + j) * 72 + ci] = v[j];
    }
  }
  __syncthreads();
  #pragma unroll
  for (int rnd = 0; rnd < 2; rnd++){
    int l = row + rnd * 32;
    u16x8 v = *(const u16x8*)&tb[l * 72 + seg * 8];
    *(u16x8*)(xT + ((size_t)b * 2050 + 1 + l0 + l) * Cc + ci0 + seg * 8) = v;
  }
  // zero pad rows 0 / 2049
  if (blockIdx.x == 0 && t < 8){
    u16x8 z = {};
    *(u16x8*)(xT + ((size_t)b * 2050 + 0) * Cc + ci0 + t * 8) = z;
  }
  if (blockIdx.x == 31 && t < 8){
    u16x8 z = {};
    *(u16x8*)(xT + ((size_t)b * 2050 + 2049) * Cc + ci0 + t * 8) = z;
  }
}

// ---------------- weight + bias repack: wp[((conv*3+k)*512+co)*512+ci] = w_conv[co][ci][k]; bb appended
__global__ __launch_bounds__(256) void pack_wb(const void* __restrict__ w0, const void* __restrict__ w1,
                                               const void* __restrict__ w2, const void* __restrict__ b0,
                                               const void* __restrict__ b1, const void* __restrict__ b2,
                                               const unsigned* __restrict__ flagp,
                                               u16* __restrict__ wp, u16* __restrict__ bb){
  int g = blockIdx.x * 256 + threadIdx.x;
  const unsigned isf32 = *flagp;
  if (g < 9 * 512 * 512){
    int ci = g & 511, co = (g >> 9) & 511, kc = g >> 18;   // kc = conv*3+k
    int conv = kc / 3, k = kc - conv * 3;
    const void* w = (conv == 0) ? w0 : ((conv == 1) ? w1 : w2);
    size_t idx = (size_t)co * 1536 + ci * 3 + k;
    wp[g] = isf32 ? f2bf(((const float*)w)[idx]) : ((const u16*)w)[idx];
  } else {
    int g2 = g - 9 * 512 * 512;
    if (g2 < 1536){
      int conv = g2 >> 9, c = g2 & 511;
      const void* bsrc = (conv == 0) ? b0 : ((conv == 1) ? b1 : b2);
      bb[g2] = isf32 ? f2bf(((const float*)bsrc)[c]) : ((const u16*)bsrc)[c];
    }
  }
}

// ---------------- fused conv GEMM, m97-style: SMALL tile + 2 independent blocks/CU.
// R10 NaN root cause: 256-thread block staged only 8 KiB of each 16 KiB region (2 rounds
// instead of 4) -> rows 64..127 uninitialized. Fixed: src[4], 4 DMA rounds per region.
// 128x128 tile, BK=64, 4 waves (2x2, per-wave 64x64), 2 bufs = 64 KiB -> 2 blocks/CU =
// two independent barrier domains filling each other's drain stalls (m114).
// 1536 blocks = exactly 3 rounds of 512. Depth-1: stage kt+1, compute kt, vmcnt(0)+barrier.
// LDS swizzle: byte ^= (row&7)<<4 (proven 0 conflicts); source pre-swizzled.
// NO launch-bounds wave minimum (R7 lesson: reg cap -> catastrophic spill).
__global__ __launch_bounds__(256) void conv_gemm_fused(const u16* __restrict__ wp, const u16* __restrict__ xT,
                                                       const u16* __restrict__ bb, u16* __restrict__ qT,
                                                       u16* __restrict__ kT, u16* __restrict__ vN){
  __shared__ u16 smem[32768];   // 64 KiB: 2 bufs x (A 128x64 + B 128x64)
  int bx = blockIdx.x;
  int b = bx & 7, inner = bx >> 3;            // b -> XCD (one batch per XCD L2)
  int mt = inner >> 4, nt = inner & 15;       // mt 0..11, nt 0..15
  int m0 = mt << 7, n0 = nt << 7;
  int conv = m0 >> 9, co0 = m0 & 511;

  int t = threadIdx.x, wave = t >> 6, lane = t & 63, quad = lane >> 4, lid = lane & 15;
  int wm_i = wave >> 1, wn_i = wave & 1;      // 2M x 2N

  // read-side swizzle: byte-col ^= (row&7)<<4; all frag rows have row%8 == lid%8
  int sx = (lid & 7) << 4;                               // byte XOR
  int cb0 = ((quad * 16) ^ sx) >> 1;                     // elem col, kh=0
  int cb1 = ((64 + quad * 16) ^ sx) >> 1;                // elem col, kh=1
  int abase0 = (wm_i * 64 + lid) * 64;                   // elem, A region (128 rows)
  int bbase0 = 8192 + (wn_i * 64 + lid) * 64;            // elem, B region (128 rows)

  // staging map (A and B regions identical shape, 16 KiB each, 4 rounds x 256 thr x 16B):
  // LDS linear byte p (row=p>>7, cb=p&127) <- global col cb ^ ((row&7)<<4)
  int src[4];
  #pragma unroll
  for (int r = 0; r < 4; r++){
    int p = t * 16 + r * 4096;                 // byte into 16 KiB region
    int row = p >> 7, c = (p & 127) ^ ((row & 7) << 4);
    src[r] = row * 512 + (c >> 1);
  }

  const u16* aGbase = wp + (size_t)(conv * 1536 + co0) * 512;
  const u16* bGbase = xT + (size_t)b * (2050 * 512) + (size_t)n0 * 512;

#define STAGE_TILE(aG, bG, stg) do{ \
    _Pragma("unroll") for (int r = 0; r < 4; ++r) \
      async_cp16((aG) + src[r], (stg) + t * 8 + r * 2048); \
    _Pragma("unroll") for (int r = 0; r < 4; ++r) \
      async_cp16((bG) + src[r], (stg) + 8192 + t * 8 + r * 2048); }while(0)

#define LOAD_A() do{ \
    _Pragma("unroll") for (int m = 0; m < 4; ++m){ \
      af[m][0] = *(const v8s*)(lds + abase0 + m * 1024 + cb0); \
      af[m][1] = *(const v8s*)(lds + abase0 + m * 1024 + cb1); } }while(0)

#define LOAD_Bn(n) do{ \
    bfc[0] = *(const v8s*)(lds + bbase0 + (n) * 1024 + cb0); \
    bfc[1] = *(const v8s*)(lds + bbase0 + (n) * 1024 + cb1); }while(0)

#define MFMA_COL(n) do{ \
    __builtin_amdgcn_s_setprio(1); \
    _Pragma("unroll") for (int m = 0; m < 4; ++m) \
    _Pragma("unroll") for (int kh = 0; kh < 2; ++kh) \
      acc[m][n] = __builtin_amdgcn_mfma_f32_16x16x32_bf16(af[m][kh], bfc[kh], acc[m][n], 0, 0, 0); \
    __builtin_amdgcn_s_setprio(0); }while(0)

  v4f acc[4][4] = {};   // [m][n]
  v8s af[4][2], bfc[2];

  // ---- prologue: stage kt=0 into buf0, drain, barrier
  STAGE_TILE(aGbase, bGbase, smem);
  asm volatile("s_waitcnt vmcnt(0)" ::: "memory");
  __builtin_amdgcn_sched_barrier(0);
  __builtin_amdgcn_s_barrier();

  // ---- main loop: 24 K-tiles (3 taps x 8 ci-steps)
  #pragma unroll 2
  for (int kt = 0; kt < 24; ++kt){
    u16* lds = smem + (kt & 1) * 16384;
    u16* stg = smem + ((kt + 1) & 1) * 16384;
    if (kt < 23){
      int k1 = kt + 1;
      int ks1 = k1 >> 3, ci1 = (k1 & 7) << 6;
      const u16* aG = aGbase + (size_t)ks1 * 262144 + ci1;
      const u16* bG = bGbase + (size_t)ks1 * 512 + ci1;
      STAGE_TILE(aG, bG, stg);
    }
    // snake columns, no intra-tile barriers
    LOAD_A();
    LOAD_Bn(0); MFMA_COL(0);
    LOAD_Bn(1); MFMA_COL(1);
    LOAD_Bn(2); MFMA_COL(2);
    LOAD_Bn(3); MFMA_COL(3);
    if (kt < 23){
      asm volatile("s_waitcnt vmcnt(0)" ::: "memory");
      __builtin_amdgcn_sched_barrier(0);
      __builtin_amdgcn_s_barrier();
    }
  }

#undef STAGE_TILE
#undef LOAD_A
#undef LOAD_Bn
#undef MFMA_COL

  // ---- epilogue
  const float qsc = (float)(1.4426950408889634 / 22.627416997969522);
  if (conv < 2){
    u16* dst = (conv == 0) ? qT : kT;
    #pragma unroll
    for (int m = 0; m < 4; ++m){
      int cog = m0 + wm_i * 64 + m * 16 + quad * 4;
      float bv[4];
      #pragma unroll
      for (int r = 0; r < 4; r++) bv[r] = bf2f(bb[cog + r]);
      int coc = cog & 511;
      #pragma unroll
      for (int n = 0; n < 4; ++n){
        int l = n0 + wn_i * 64 + n * 16 + lid;
        u16x4 pk;
        #pragma unroll
        for (int r = 0; r < 4; r++){
          float v = acc[m][n][r] + bv[r];
          if (conv == 0) v *= qsc;
          pk[r] = f2bf(v);
        }
        *(u16x4*)(dst + ((((size_t)b * Hh + (coc >> 6)) * Ll + l) << 6) + (coc & 63)) = pk;
      }
    }
  } else {
    // v: LDS-bounce transpose -> vectorized [b][co][l] stores. scr = [128 co][132]
    u16* scr = smem;
    __syncthreads();
    #pragma unroll
    for (int m = 0; m < 4; ++m){
      int rloc = wm_i * 64 + m * 16 + quad * 4;
      int cog = m0 + rloc;
      float bv[4];
      #pragma unroll
      for (int r = 0; r < 4; r++) bv[r] = bf2f(bb[cog + r]);
      #pragma unroll
      for (int n = 0; n < 4; ++n){
        int lcl = wn_i * 64 + n * 16 + lid;
        #pragma unroll
        for (int r = 0; r < 4; r++)
          scr[(rloc + r) * 132 + lcl] = f2bf(acc[m][n][r] + bv[r]);
      }
    }
    __syncthreads();
    int seg = t & 15, rw = t >> 4;        // seg 0..15 (8-elem cols = 128), rw 0..15
    #pragma unroll
    for (int ps = 0; ps < 8; ++ps){
      int row = rw + ps * 16;
      u16x8 vv = *(const u16x8*)&scr[row * 132 + seg * 8];
      *(u16x8*)(vN + (((size_t)b * Cc + co0 + row) << 11) + n0 + seg * 8) = vv;
    }
  }
}

// ---------------- flash attention: 8-wave (512-thread) blocks for TLP — 512 blocks,
// 2 blocks/CU resident (LDS-limited: 64 KiB/block), 16 waves/CU (50% occupancy).
// NO launch-bounds wave minimum: LDS already pins occupancy; a register cap here caused
// a catastrophic spill (R7: VGPR 64, 715 MB scratch writes, 3.3x slowdown).
// Each wave owns 32 Q-rows; K/V double-buffered, counted vmcnt (4 DMAs/thread: K2+V2;
// waits 2/4/2, never 0 in loop). V LDS split into two [64][64] half-tiles (128B rows,
// conv-proven 0-conflict XOR). Fixed-max softmax, lsum via ones-MFMA, setprio.
__global__ __launch_bounds__(512) void attn_kernel(const u16* __restrict__ qT, const u16* __restrict__ kT,
                                                   const u16* __restrict__ vN, const unsigned* __restrict__ flagp,
                                                   void* __restrict__ outv){
  int bhx = blockIdx.x;                 // 0..63
  int b = bhx >> 3, h = bhx & 7, l0 = blockIdx.y * 256;
  int t = threadIdx.x, w = t >> 6, lane = t & 63, quad = lane >> 4, lid = lane & 15;
  __shared__ u16 kls[2][8192];          // K tile [slot 128][d 64], XOR-swizzled
  __shared__ u16 vls[2][8192];          // V tile [half 2][d 64][m 64], XOR-swizzled
  const unsigned isf32 = *flagp;
  const size_t bh = (size_t)b * Hh + h;
  const int xk = (lid & 7) << 3;        // read-side elem XOR (8-elem granule)

  // staging maps (loop-invariant): dest linear e=(r*512+t)*8; source pre-swizzled.
  // K: slot=e>>6 col=e&63; global row = perm(slot); col ^= (slot&7)<<3.
  // V: half=e>>12 d=(e>>6)&63 col=e&63; global elem = d*2048 + half*64 + (col^((d&7)<<3)).
  int kadd[2], vadd[2];
  #pragma unroll
  for (int r = 0; r < 2; r++){
    int e = (r * 512 + t) * 8;
    int slot = e >> 6, col = e & 63;
    int s5 = slot & 31;
    int m = (slot & ~31) | (((s5 >> 2) & 1) << 3) | (((s5 >> 3) & 1) << 4) | (((s5 >> 4) & 1) << 2) | (s5 & 3);
    kadd[r] = m * 64 + (col ^ ((slot & 7) << 3));
    int half = e >> 12, d = (e >> 6) & 63;
    vadd[r] = d * Ll + half * 64 + (col ^ ((d & 7) << 3));
  }
  const u16* kTb = kT + bh * Ll * 64;
  const u16* vNb = vN + ((size_t)(b * Cc + h * Dh)) * Ll;

#define STAGE_KV(mt1) do{ \
    const u16* kp = kTb + (size_t)(mt1) * 8192; \
    const u16* vp = vNb + (mt1) * 128; \
    u16* kd = &kls[(mt1) & 1][0]; \
    u16* vd = &vls[(mt1) & 1][0]; \
    async_cp16(kp + kadd[0], kd + t * 8); \
    async_cp16(kp + kadd[1], kd + 4096 + t * 8); \
    async_cp16(vp + vadd[0], vd + t * 8); \
    async_cp16(vp + vadd[1], vd + 4096 + t * 8); }while(0)

  // Q fragments in registers (B-operand of S^T GEMM) — issued BEFORE staging so the
  // prologue vmcnt(2) also certifies them (V(0)'s 2 DMAs are the only ones left in flight)
  v8s qF[2][2];
  #pragma unroll
  for (int ci = 0; ci < 2; ci++)
    #pragma unroll
    for (int ks = 0; ks < 2; ks++)
      qF[ci][ks] = *(const v8s*)(qT + ((bh * Ll) + l0 + w * 32 + ci * 16 + lid) * 64 + ks * 32 + quad * 8);
  __builtin_amdgcn_sched_barrier(0);

  const v8s onesF = {0x3F80, 0x3F80, 0x3F80, 0x3F80, 0x3F80, 0x3F80, 0x3F80, 0x3F80};
  v4f o[2][4] = {};                // [ci][df]
  v4f o1[2] = {};                  // lsum accumulators (all cols equal)

  // prologue: stage mt=0; certify Q + K(0) (leave V(0)'s 2 DMAs in flight)
  STAGE_KV(0);
  asm volatile("s_waitcnt vmcnt(2)" ::: "memory");
  __builtin_amdgcn_sched_barrier(0);
  __builtin_amdgcn_s_barrier();

  for (int mt = 0; mt < 16; mt++){
    if (mt < 15) STAGE_KV(mt + 1);              // 4 DMAs; V(mt)'s 2 still in flight
    const u16* kcur = &kls[mt & 1][0];
    const u16* vcur = &vls[mt & 1][0];

    // S^T: s[c][tt][ci] reg r = S^T[m0 + c*32 + quad*8 + tt*4 + r][w*32+ci*16+lid]
    v4f s[4][2][2] = {};
    #pragma unroll
    for (int ks = 0; ks < 2; ks++){
      v8s aF[4][2];
      #pragma unroll
      for (int c = 0; c < 4; c++)
        #pragma unroll
        for (int tt = 0; tt < 2; tt++)
          aF[c][tt] = *(const v8s*)&kcur[(c * 32 + tt * 16 + lid) * 64 + ((ks * 32 + quad * 8) ^ xk)];
      __builtin_amdgcn_s_setprio(1);
      #pragma unroll
      for (int c = 0; c < 4; c++)
        #pragma unroll
        for (int tt = 0; tt < 2; tt++){
          s[c][tt][0] = __builtin_amdgcn_mfma_f32_16x16x32_bf16(aF[c][tt], qF[0][ks], s[c][tt][0], 0, 0, 0);
          s[c][tt][1] = __builtin_amdgcn_mfma_f32_16x16x32_bf16(aF[c][tt], qF[1][ks], s[c][tt][1], 0, 0, 0);
        }
      __builtin_amdgcn_s_setprio(0);
    }

    // V(mt) certified for all waves: own-wave counted wait + barrier
    if (mt < 15){
      asm volatile("s_waitcnt vmcnt(4)" ::: "memory");   // V(mt) landed; K/V(mt+1) in flight
    } else {
      asm volatile("s_waitcnt vmcnt(0)" ::: "memory");
    }
    __builtin_amdgcn_sched_barrier(0);
    __builtin_amdgcn_s_barrier();

    // fixed-max softmax: p = exp2(s) packed straight into PV A-frags; lsum via ones-MFMA
    #pragma unroll
    for (int c = 0; c < 4; c++){
      v8s aP[2];
      #pragma unroll
      for (int ci = 0; ci < 2; ci++){
        float p[8];
        #pragma unroll
        for (int tt = 0; tt < 2; tt++)
          #pragma unroll
          for (int r = 0; r < 4; r++)
            p[tt * 4 + r] = EXP2F(s[c][tt][ci][r]);
        unsigned u[4];
        #pragma unroll
        for (int k2 = 0; k2 < 4; k2++){
          __hip_bfloat162 hb = __float22bfloat162_rn(make_float2(p[2 * k2], p[2 * k2 + 1]));
          __builtin_memcpy(&u[k2], &hb, 4);
        }
        __builtin_memcpy(&aP[ci], u, 16);
      }
      // V reads: half-tile layout, 128B rows, conv-proven XOR pattern
      v8s bV[4];
      #pragma unroll
      for (int df = 0; df < 4; df++)
        bV[df] = *(const v8s*)&vcur[(c >> 1) * 4096 + (df * 16 + lid) * 64 + ((((c & 1) * 32) + quad * 8) ^ xk)];
      __builtin_amdgcn_s_setprio(1);
      #pragma unroll
      for (int ci = 0; ci < 2; ci++){
        #pragma unroll
        for (int df = 0; df < 4; df++)
          o[ci][df] = __builtin_amdgcn_mfma_f32_16x16x32_bf16(aP[ci], bV[df], o[ci][df], 0, 0, 0);
        o1[ci] = __builtin_amdgcn_mfma_f32_16x16x32_bf16(aP[ci], onesF, o1[ci], 0, 0, 0);
      }
      __builtin_amdgcn_s_setprio(0);
    }

    // end of phase: certify K(mt+1) (own-wave) before barrier; V(mt+1) stays in flight
    if (mt < 15){
      asm volatile("s_waitcnt vmcnt(2)" ::: "memory");
      __builtin_amdgcn_sched_barrier(0);
      __builtin_amdgcn_s_barrier();
    }
  }
#undef STAGE_KV

  #pragma unroll
  for (int lf = 0; lf < 2; lf++){
    v4f nv;
    #pragma unroll
    for (int r = 0; r < 4; r++) nv[r] = 1.f / o1[lf][r];
    #pragma unroll
    for (int df = 0; df < 4; df++){
      int d = df * 16 + lid;
      int l = l0 + w * 32 + lf * 16 + quad * 4;
      size_t ofs = (((bh << 6) + d) << 11) + l;
      if (isf32){
        v4f st;
        #pragma unroll
        for (int r = 0; r < 4; r++) st[r] = o[lf][df][r] * nv[r];
        *(v4f*)((float*)outv + ofs) = st;
      } else {
        u16x4 pk;
        #pragma unroll
        for (int r = 0; r < 4; r++) pk[r] = f2bf(o[lf][df][r] * nv[r]);
        *(u16x4*)((u16*)outv + ofs) = pk;
      }
    }
  }
}

extern "C" void kernel_launch(void* const* d_in, const int* in_sizes, int n_in,
                              void* d_out, int out_size, void* d_ws, size_t ws_size,
                              hipStream_t stream){
  const void* x  = d_in[0];
  const void* w0 = d_in[1];
  const void* b0 = d_in[2];
  const void* w1 = d_in[3];
  const void* b1 = d_in[4];
  const void* w2 = d_in[5];
  const void* b2 = d_in[6];
  u16* ws = (u16*)d_ws;
  unsigned* flag = (unsigned*)ws;                // 1 u32 at base (64 u16 slot, aligned)
  u16* xT = ws + 64;                             // [8][2050][512]
  u16* wp = xT + (size_t)8 * 2050 * 512;         // [9][512][512]
  u16* bb = wp + (size_t)9 * 512 * 512;          // [3][512]
  u16* qT = bb + 1536;                           // [8][8][2048][64]
  u16* kT = qT + (size_t)8 * 8 * 2048 * 64;
  u16* vN = kT + (size_t)8 * 8 * 2048 * 64;      // [8][512][2048]

  detect_dtype<<<1, 256, 0, stream>>>((const u16*)x, flag);
  transpose_pad<<<dim3(32, 8, 8), 256, 0, stream>>>(x, flag, xT);
  pack_wb<<<dim3(9 * 512 * 512 / 256 + 6), 256, 0, stream>>>(w0, w1, w2, b0, b1, b2, flag, wp, bb);
  conv_gemm_fused<<<dim3(1536), 256, 0, stream>>>(wp, xT, bb, qT, kT, vN);
  attn_kernel<<<dim3(64, 8), 512, 0, stream>>>(qT, kT, vN, flag, d_out);
}